// Round 4
// baseline (238.986 us; speedup 1.0000x reference)
//
#include <hip/hip_runtime.h>
#include <math.h>

typedef short short8 __attribute__((ext_vector_type(8)));
typedef float floatx4 __attribute__((ext_vector_type(4)));
typedef float floatx2 __attribute__((ext_vector_type(2)));

#define B_ROWS 8192
#define L_DIM 64
#define Y_EMB 128
#define Y_HID 128
#define E_HID 32
#define MAP_HID 256
#define MAX_LABELS 200
#define Y_MID 128
#define E_MID 16
#define CAT_F 160

__device__ __forceinline__ unsigned short f2b(float f) {
  union { float f; unsigned int i; } v; v.f = f;
  unsigned int r = (v.i + 0x7fffu + ((v.i >> 16) & 1u)) >> 16;
  return (unsigned short)r;
}
__device__ __forceinline__ float gelu_exact(float x) {
  float u = 0.7978845608028654f * x * fmaf(0.044715f, x * x, 1.0f);
  return 0.5f * x * (1.0f + tanhf(u));
}
// 4-term Taylor of tanh-gelu: err < 2e-4 for |x|<=0.5 (e-branch pre-acts)
__device__ __forceinline__ float gelu_small(float x) {
  float x2 = x * x;
  float t = fmaf(-0.0668178f, x2, 0.39894228f);
  return x * fmaf(x, t, 0.5f);
}

__device__ __forceinline__ void gl_lds16(const void* g, void* l) {
  __builtin_amdgcn_global_load_lds(
      (const __attribute__((address_space(1))) unsigned int*)g,
      (__attribute__((address_space(3))) unsigned int*)l, 16, 0, 0);
}

template <int CTRL>
__device__ __forceinline__ float dpp_add(float v) {
  int t = __builtin_amdgcn_update_dpp(0, __float_as_int(v), CTRL, 0xf, 0xf, true);
  return v + __int_as_float(t);
}
// butterfly sum over the 16-lane DPP row (l15 dimension)
__device__ __forceinline__ float red16(float v) {
  v = dpp_add<0xB1>(v);   // quad_perm xor1
  v = dpp_add<0x4E>(v);   // quad_perm xor2
  v = dpp_add<0x141>(v);  // row_half_mirror
  v = dpp_add<0x140>(v);  // row_mirror
  return v;
}

// ---- fused prep kernel ----
// blocks [0,320):    wprep  (l = b/5, kc = b%5) -> Wtc[l][kc][n][32] bf16 + hb1p
// blocks [320,1344): yemb   (8 rows/block f32 row-copy)
// blocks [1344,1444): yh    (2 labels/block -> tbl bf16)
__global__ void prep_kernel(const float* __restrict__ hW1,
                            const float* __restrict__ hb1,
                            const float* __restrict__ eW2,
                            const float* __restrict__ eb2,
                            const float* __restrict__ emb,
                            const float* __restrict__ yW1,
                            const float* __restrict__ yb1,
                            const float* __restrict__ yW2,
                            const float* __restrict__ yb2,
                            const int* __restrict__ y,
                            unsigned short* __restrict__ Wtc,
                            float* __restrict__ hb1p,
                            unsigned short* __restrict__ tbl,
                            uint4* __restrict__ outemb) {
  __shared__ float sh[576];
  const int bid = blockIdx.x;
  const int t = threadIdx.x;
  if (bid < 320) {
    const int l = bid / 5;
    const int kc = bid - l * 5;
    const int n = t;
    const float* W = hW1 + (size_t)l * CAT_F * MAP_HID;
    unsigned short* dst = Wtc + (((size_t)l * 5 + kc) * MAP_HID + n) * 32;
    if (kc < 4) {
#pragma unroll
      for (int g = 0; g < 4; ++g) {
        short8 o;
#pragma unroll
        for (int j = 0; j < 8; ++j)
          o[j] = (short)f2b(W[(size_t)(kc * 32 + g * 8 + j) * MAP_HID + n]);
        *(short8*)&dst[g * 8] = o;
      }
    } else {
      float* sE = sh;          // 512
      float* sB = sh + 512;    // 32
      sE[n] = eW2[n];
      sE[n + 256] = eW2[n + 256];
      if (n < E_HID) sB[n] = eb2[n];
      __syncthreads();
      float accW[E_MID];
#pragma unroll
      for (int j = 0; j < E_MID; ++j) accW[j] = 0.f;
      float hacc = 0.f;
      for (int i = 0; i < E_HID; ++i) {
        float v = W[(size_t)(128 + i) * MAP_HID + n];
        hacc = fmaf(sB[i], v, hacc);
#pragma unroll
        for (int j = 0; j < E_MID; ++j) accW[j] = fmaf(sE[j * E_HID + i], v, accW[j]);
      }
      short8 p1, p2;
#pragma unroll
      for (int j = 0; j < 8; ++j) { p1[j] = (short)f2b(accW[j]); p2[j] = (short)f2b(accW[8 + j]); }
      *(short8*)&dst[0] = p1;
      *(short8*)&dst[8] = p2;
      *(short8*)&dst[16] = (short8){0, 0, 0, 0, 0, 0, 0, 0};
      *(short8*)&dst[24] = (short8){0, 0, 0, 0, 0, 0, 0, 0};
      hb1p[l * MAP_HID + n] = hb1[l * MAP_HID + n] + hacc;
    }
  } else if (bid < 1344) {
    const int row = (bid - 320) * 8 + (t >> 5);
    const int c = t & 31;
    outemb[row * 32 + c] = ((const uint4*)emb)[y[row] * 32 + c];
  } else {
    const int lab = (bid - 1344) * 2 + (t >> 7);
    const int j = t & 127;
    float* mid = sh + (t >> 7) * 128;
    float acc = yb1[j];
    for (int c = 0; c < Y_EMB; ++c)
      acc = fmaf(emb[lab * Y_EMB + c], yW1[c * Y_MID + j], acc);
    mid[j] = gelu_exact(acc);
    __syncthreads();
    float acc2 = yb2[j];
    for (int c = 0; c < Y_MID; ++c)
      acc2 = fmaf(mid[c], yW2[c * Y_HID + j], acc2);
    tbl[lab * Y_HID + j] = f2b(acc2);
  }
}

// ---- main fused GEMM ----
__launch_bounds__(256, 3)
__global__ void main_kernel(const int* __restrict__ y,
                            const float* __restrict__ e,       // [8192][64]
                            const float* __restrict__ eW1,     // [16]
                            const float* __restrict__ eb1,     // [16]
                            const unsigned short* __restrict__ tbl,   // [200][128] bf16
                            const unsigned short* __restrict__ Wtc,   // [64][5][256][32] bf16
                            const float* __restrict__ hb1p,    // [64][256]
                            const float* __restrict__ hW2,     // [64][256]
                            const float* __restrict__ hb2,     // [64]
                            float* __restrict__ outh) {        // [8192][64]
  const int l = blockIdx.y;
  const int b0 = blockIdx.x * 512;
  const int tid = threadIdx.x;
  const int w = tid >> 6;
  const int lane = tid & 63;
  const int l15 = lane & 15, q = lane >> 4;

  __shared__ __align__(16) unsigned short As[2][4][64][32];  // 32 KB, 16B-slot swizzled
  __shared__ __align__(16) unsigned short Gs[2][64][20];     // 5 KB (40B rows: conflict-free)
  __shared__ float red[2][4][64];                            // 2 KB

  // B fragments: 80 VGPRs, resident for whole block
  short8 bfrag[5][4];
#pragma unroll
  for (int kc = 0; kc < 5; ++kc)
#pragma unroll
    for (int ni = 0; ni < 4; ++ni)
      bfrag[kc][ni] = *(const short8*)&Wtc[(((size_t)l * 5 + kc) * MAP_HID + w * 64 + ni * 16 + l15) * 32 + q * 8];

  float hv[4], hb1v[4];
#pragma unroll
  for (int ni = 0; ni < 4; ++ni) {
    int n = w * 64 + ni * 16 + l15;
    hv[ni] = hW2[l * MAP_HID + n];
    hb1v[ni] = hb1p[l * MAP_HID + n];
  }
  const float hb2l = hb2[l];

  const int gj = lane & 1;
  const float4 w1a = *(const float4*)&eW1[gj * 8];
  const float4 w1b = *(const float4*)&eW1[gj * 8 + 4];
  const float4 b1a = *(const float4*)&eb1[gj * 8];
  const float4 b1b = *(const float4*)&eb1[gj * 8 + 4];

  auto stage = [&](int mt, int bb) {
    const int bR0 = b0 + mt * 64;
    {
      const int kc = w;                 // wave w stages A-chunk kc=w (y_h 4 chunks)
      const int row = lane >> 2;        // 0..15 within 16-row group
      const int k16 = lane & 3;
      const int k16s = k16 ^ ((row >> 1) & 3);  // swizzled source slot
#pragma unroll
      for (int j = 0; j < 4; ++j) {
        int lab = y[bR0 + j * 16 + row];
        const unsigned short* src = tbl + (size_t)lab * 128 + kc * 32 + k16s * 8;
        gl_lds16(src, &As[bb][kc][j * 16][0]);
      }
    }
    if (w < 2) {  // waves 0,1: 16 G features inline, 8 per lane
      const int row = w * 32 + (lane >> 1);
      float x = e[(size_t)(bR0 + row) * 64 + l];
      short8 gv;
      gv[0] = (short)f2b(gelu_small(fmaf(x, w1a.x, b1a.x)));
      gv[1] = (short)f2b(gelu_small(fmaf(x, w1a.y, b1a.y)));
      gv[2] = (short)f2b(gelu_small(fmaf(x, w1a.z, b1a.z)));
      gv[3] = (short)f2b(gelu_small(fmaf(x, w1a.w, b1a.w)));
      gv[4] = (short)f2b(gelu_small(fmaf(x, w1b.x, b1b.x)));
      gv[5] = (short)f2b(gelu_small(fmaf(x, w1b.y, b1b.y)));
      gv[6] = (short)f2b(gelu_small(fmaf(x, w1b.z, b1b.z)));
      gv[7] = (short)f2b(gelu_small(fmaf(x, w1b.w, b1b.w)));
      *(short8*)&Gs[bb][row][gj * 8] = gv;
    }
  };

  stage(0, 0);
  __syncthreads();
  int buf = 0;
  const floatx2 C0 = {0.39894228f, 0.39894228f};
  const floatx2 H5 = {0.5f, 0.5f};
  for (int mt = 0; mt < 8; ++mt) {
    if (mt < 7) stage(mt + 1, buf ^ 1);  // async prefetch, drained at the barrier

    floatx4 acc[4][4];
#pragma unroll
    for (int mi = 0; mi < 4; ++mi)
#pragma unroll
      for (int ni = 0; ni < 4; ++ni)
        acc[mi][ni] = (floatx4){hb1v[ni], hb1v[ni], hb1v[ni], hb1v[ni]};

    const int sel = (l15 >> 1) & 3;
#pragma unroll
    for (int kc = 0; kc < 4; ++kc) {
      short8 afr[4];
#pragma unroll
      for (int mi = 0; mi < 4; ++mi)
        afr[mi] = *(const short8*)&As[buf][kc][mi * 16 + l15][(q ^ sel) * 8];
#pragma unroll
      for (int mi = 0; mi < 4; ++mi)
#pragma unroll
        for (int ni = 0; ni < 4; ++ni)
          acc[mi][ni] = __builtin_amdgcn_mfma_f32_16x16x32_bf16(afr[mi], bfrag[kc][ni], acc[mi][ni], 0, 0, 0);
    }
    {  // kc=4: G features; q=2,3 read defined data x zero-B columns
      short8 afr[4];
#pragma unroll
      for (int mi = 0; mi < 4; ++mi)
        afr[mi] = *(const short8*)&Gs[buf][mi * 16 + l15][(q & 1) * 8];
#pragma unroll
      for (int mi = 0; mi < 4; ++mi)
#pragma unroll
        for (int ni = 0; ni < 4; ++ni)
          acc[mi][ni] = __builtin_amdgcn_mfma_f32_16x16x32_bf16(afr[mi], bfrag[4][ni], acc[mi][ni], 0, 0, 0);
    }

    // epilogue: packed-f32 gelu(h1)·hW2, DPP butterfly over cols (l15)
#pragma unroll
    for (int mi = 0; mi < 4; ++mi) {
      floatx2 s01 = {0.f, 0.f}, s23 = {0.f, 0.f};
#pragma unroll
      for (int ni = 0; ni < 4; ++ni) {
        floatx4 a = acc[mi][ni];
        floatx2 a01 = {a[0], a[1]};
        floatx2 a23 = {a[2], a[3]};
        floatx2 hvv = {hv[ni], hv[ni]};
        floatx2 t01 = __builtin_elementwise_fma(a01, C0, H5);
        floatx2 t23 = __builtin_elementwise_fma(a23, C0, H5);
        floatx2 g01 = a01 * t01;   // gelu2(x) = x*(0.5 + 0.39894228 x)
        floatx2 g23 = a23 * t23;
        s01 = __builtin_elementwise_fma(g01, hvv, s01);
        s23 = __builtin_elementwise_fma(g23, hvv, s23);
      }
      float s0 = red16(s01[0]);
      float s1 = red16(s01[1]);
      float s2 = red16(s23[0]);
      float s3 = red16(s23[1]);
      if (l15 == 0) red[buf][w][mi * 16 + q * 4 + 0] = s0;
      if (l15 == 1) red[buf][w][mi * 16 + q * 4 + 1] = s1;
      if (l15 == 2) red[buf][w][mi * 16 + q * 4 + 2] = s2;
      if (l15 == 3) red[buf][w][mi * 16 + q * 4 + 3] = s3;
    }
    __syncthreads();  // single barrier per m-tile: covers red + staged buffers
    if (w == (mt & 3)) {  // rotating finisher wave
      float s = red[buf][0][lane] + red[buf][1][lane] + red[buf][2][lane] + red[buf][3][lane] + hb2l;
      outh[(size_t)(b0 + mt * 64 + lane) * 64 + l] = tanhf(3.0f * s);
    }
    buf ^= 1;
  }
}

extern "C" void kernel_launch(void* const* d_in, const int* in_sizes, int n_in,
                              void* d_out, int out_size, void* d_ws, size_t ws_size,
                              hipStream_t stream) {
  const int* y     = (const int*)d_in[0];
  const float* e   = (const float*)d_in[1];
  const float* emb = (const float*)d_in[2];
  const float* yW1 = (const float*)d_in[3];
  const float* yb1 = (const float*)d_in[4];
  const float* yW2 = (const float*)d_in[5];
  const float* yb2 = (const float*)d_in[6];
  const float* eW1 = (const float*)d_in[7];
  const float* eb1 = (const float*)d_in[8];
  const float* eW2 = (const float*)d_in[9];
  const float* eb2 = (const float*)d_in[10];
  const float* hW1 = (const float*)d_in[11];
  const float* hb1 = (const float*)d_in[12];
  const float* hW2 = (const float*)d_in[13];
  const float* hb2 = (const float*)d_in[14];

  float* outh   = (float*)d_out;                                     // h: [8192][64]
  uint4* outemb = (uint4*)((float*)d_out + (size_t)B_ROWS * L_DIM);  // y_embed f32 [8192][128]

  unsigned short* tbl  = (unsigned short*)d_ws;                           // 200*128 bf16 (pad 64KB)
  unsigned short* Wtc  = (unsigned short*)((char*)d_ws + 65536);          // 64*5*256*32 bf16 = 5.24MB
  float*          hb1p = (float*)((char*)d_ws + 65536 + 5242880);         // 64*256 f32

  prep_kernel<<<dim3(1444), dim3(256), 0, stream>>>(hW1, hb1, eW2, eb2, emb, yW1, yb1,
                                                    yW2, yb2, y, Wtc, hb1p, tbl, outemb);
  main_kernel<<<dim3(16, 64), dim3(256), 0, stream>>>(y, e, eW1, eb1, tbl, Wtc, hb1p, hW2, hb2, outh);
}

// Round 5
// 125.931 us; speedup vs baseline: 1.8977x; 1.8977x over previous
//
#include <hip/hip_runtime.h>
#include <math.h>

typedef short short8 __attribute__((ext_vector_type(8)));
typedef float floatx4 __attribute__((ext_vector_type(4)));

#define B_ROWS 8192
#define L_DIM 64
#define MAXL 200
#define GC 0.39894228f
#define GD 0.0668178f

// workspace offsets (bytes)
#define OFF_TBLB 0u          // bf16 [256][128] (rows 200..255 zeroed)
#define OFF_WTC  65536u      // bf16 [64][4][256][32]
#define OFF_HB1P 4259840u    // f32 [64][256]
#define OFF_P    4325376u    // f32 [64][4][256]  (P1..P4)
#define OFF_Q    4587520u    // f32 [64][8]       (q for x^2..x^8 at 0..6)
#define OFF_CA8  4589568u    // f32 [64][256][8]  (C,A1,A2,A3,A4,-,-,-)

__device__ __forceinline__ unsigned short f2b(float f) {
  union { float f; unsigned int i; } v; v.f = f;
  unsigned int r = (v.i + 0x7fffu + ((v.i >> 16) & 1u)) >> 16;
  return (unsigned short)r;
}
__device__ __forceinline__ float gelu_exact(float x) {
  float u = 0.7978845608028654f * x * fmaf(0.044715f, x * x, 1.0f);
  return 0.5f * x * (1.0f + tanhf(u));
}

__device__ __forceinline__ void gl_lds16(const void* g, void* l) {
  __builtin_amdgcn_global_load_lds(
      (const __attribute__((address_space(1))) unsigned int*)g,
      (__attribute__((address_space(3))) unsigned int*)l, 16, 0, 0);
}

template <int CTRL>
__device__ __forceinline__ float dpp_add(float v) {
  int t = __builtin_amdgcn_update_dpp(0, __float_as_int(v), CTRL, 0xf, 0xf, true);
  return v + __int_as_float(t);
}
__device__ __forceinline__ float red16(float v) {
  v = dpp_add<0xB1>(v);   // quad_perm xor1
  v = dpp_add<0x4E>(v);   // quad_perm xor2
  v = dpp_add<0x141>(v);  // row_half_mirror
  v = dpp_add<0x140>(v);  // row_mirror
  return v;
}

// ================= prep kernel =================
// [0,256):    Wtc bf16 chunks (l=bid>>2, kc=bid&3)
// [256,320):  per-l: W' = eW2@hW1_e -> P1..P4, hb1p (all bias folded), Q (delta^2 coeffs)
// [320,1344): y_embed output copy
// [1344,1444): y_h table (2 labels/block) -> tblb bf16
// 1444:       zero tblb pad rows 200..255
__global__ void prep_kernel(const float* __restrict__ hW1, const float* __restrict__ hb1,
                            const float* __restrict__ eW1, const float* __restrict__ eb1,
                            const float* __restrict__ eW2, const float* __restrict__ eb2,
                            const float* __restrict__ emb,
                            const float* __restrict__ yW1, const float* __restrict__ yb1,
                            const float* __restrict__ yW2, const float* __restrict__ yb2,
                            const int* __restrict__ y, const float* __restrict__ hW2,
                            unsigned short* __restrict__ tblb,
                            unsigned short* __restrict__ Wtc,
                            float* __restrict__ hb1p, float* __restrict__ P,
                            float* __restrict__ Q, uint4* __restrict__ outemb) {
  __shared__ float sh[2048];
  const int bid = blockIdx.x;
  const int t = threadIdx.x;
  if (bid < 256) {
    const int l = bid >> 2, kc = bid & 3;
    const float* W = hW1 + (size_t)l * 160 * 256;
    unsigned short* dst = Wtc + (((size_t)l * 4 + kc) * 256 + t) * 32;
#pragma unroll
    for (int g = 0; g < 4; ++g) {
      short8 o;
#pragma unroll
      for (int j = 0; j < 8; ++j)
        o[j] = (short)f2b(W[(size_t)(kc * 32 + g * 8 + j) * 256 + t]);
      *(short8*)&dst[g * 8] = o;
    }
  } else if (bid < 320) {
    const int l = bid - 256;
    sh[t] = eW2[t];                 // eW2: [16][32]
    sh[t + 256] = eW2[t + 256];
    if (t < 32) sh[512 + t] = eb2[t];
    __syncthreads();
    const float* W = hW1 + (size_t)l * 160 * 256;
    float accW[16];
#pragma unroll
    for (int j = 0; j < 16; ++j) accW[j] = 0.f;
    float hacc = 0.f;
    for (int i = 0; i < 32; ++i) {
      float v = W[(size_t)(128 + i) * 256 + t];
      hacc = fmaf(sh[512 + i], v, hacc);
#pragma unroll
      for (int j = 0; j < 16; ++j) accW[j] = fmaf(sh[j * 32 + i], v, accW[j]);
    }
    // gelu_small(w x + b) = e0 + e1 x + e2 x^2 + e3 x^3 + e4 x^4
    float P0 = 0.f, P1 = 0.f, P2 = 0.f, P3 = 0.f, P4 = 0.f;
    for (int j = 0; j < 16; ++j) {
      float w = eW1[j], b = eb1[j];
      float w2 = w * w, b2 = b * b;
      float e0 = 0.5f * b + GC * b2 - GD * b2 * b2;
      float e1 = w * (0.5f + 2.f * GC * b - 4.f * GD * b * b2);
      float e2 = w2 * (GC - 6.f * GD * b2);
      float e3 = -4.f * GD * w2 * w * b;
      float e4 = -GD * w2 * w2;
      float a = accW[j];
      P0 = fmaf(e0, a, P0); P1 = fmaf(e1, a, P1); P2 = fmaf(e2, a, P2);
      P3 = fmaf(e3, a, P3); P4 = fmaf(e4, a, P4);
    }
    hb1p[l * 256 + t] = hb1[l * 256 + t] + hacc + P0;
    P[((size_t)l * 4 + 0) * 256 + t] = P1;
    P[((size_t)l * 4 + 1) * 256 + t] = P2;
    P[((size_t)l * 4 + 2) * 256 + t] = P3;
    P[((size_t)l * 4 + 3) * 256 + t] = P4;
    __syncthreads();  // done with sE/sB
    float cw = GC * hW2[l * 256 + t];
    sh[t * 8 + 0] = cw * P1 * P1;                          // x^2
    sh[t * 8 + 1] = cw * 2.f * P1 * P2;                    // x^3
    sh[t * 8 + 2] = cw * (2.f * P1 * P3 + P2 * P2);        // x^4
    sh[t * 8 + 3] = cw * 2.f * (P1 * P4 + P2 * P3);        // x^5
    sh[t * 8 + 4] = cw * (2.f * P2 * P4 + P3 * P3);        // x^6
    sh[t * 8 + 5] = cw * 2.f * P3 * P4;                    // x^7
    sh[t * 8 + 6] = cw * P4 * P4;                          // x^8
    __syncthreads();
    if (t < 7) {
      float s = 0.f;
      for (int n = 0; n < 256; ++n) s += sh[n * 8 + t];
      Q[l * 8 + t] = s;
    }
  } else if (bid < 1344) {
    const int row = (bid - 320) * 8 + (t >> 5);
    const int c = t & 31;
    outemb[row * 32 + c] = ((const uint4*)emb)[y[row] * 32 + c];
  } else if (bid < 1444) {
    const int lab = (bid - 1344) * 2 + (t >> 7);
    const int j = t & 127;
    float* mid = sh + (t >> 7) * 128;
    float acc = yb1[j];
    for (int c = 0; c < 128; ++c)
      acc = fmaf(emb[lab * 128 + c], yW1[c * 128 + j], acc);
    mid[j] = gelu_exact(acc);
    __syncthreads();
    float acc2 = yb2[j];
    for (int c = 0; c < 128; ++c)
      acc2 = fmaf(mid[c], yW2[c * 128 + j], acc2);
    tblb[lab * 128 + j] = f2b(acc2);
  } else {
    unsigned int* tz = (unsigned int*)tblb;
    for (int i = t; i < 3584; i += 256) tz[12800 + i] = 0u;  // rows 200..255
  }
}

// ================= table GEMM: U = tblb @ hW1_y + bias -> C, A1..A4 =================
__global__ void tblgemm_kernel(const unsigned short* __restrict__ tblb,
                               const unsigned short* __restrict__ Wtc,
                               const float* __restrict__ hb1p,
                               const float* __restrict__ P,
                               const float* __restrict__ hW2,
                               const float* __restrict__ hb2,
                               float* __restrict__ CA8) {
  const int l = blockIdx.y;
  const int m0 = blockIdx.x * 64;   // lab tile base
  const int tid = threadIdx.x;
  const int w = tid >> 6, lane = tid & 63;
  const int l15 = lane & 15, q = lane >> 4;

  __shared__ __align__(16) unsigned short As[4][64][32];  // 16 KB, swizzled slots
  __shared__ float red[4][64][8];                         // 8 KB

  short8 bfrag[4][4];
#pragma unroll
  for (int kc = 0; kc < 4; ++kc)
#pragma unroll
    for (int ni = 0; ni < 4; ++ni)
      bfrag[kc][ni] = *(const short8*)&Wtc[(((size_t)l * 4 + kc) * 256 + w * 64 + ni * 16 + l15) * 32 + q * 8];

  float hv[4], hb1v[4], Pv[4][4];
#pragma unroll
  for (int ni = 0; ni < 4; ++ni) {
    int n = w * 64 + ni * 16 + l15;
    hv[ni] = hW2[l * 256 + n];
    hb1v[ni] = hb1p[l * 256 + n];
#pragma unroll
    for (int k = 0; k < 4; ++k) Pv[k][ni] = P[((size_t)l * 4 + k) * 256 + n];
  }
  const float hb2l = hb2[l];

  {  // stage A: wave w loads kc=w chunk for all 64 rows
    const int kc = w;
    const int row = lane >> 2;
    const int k16 = lane & 3;
    const int k16s = k16 ^ ((row >> 1) & 3);
#pragma unroll
    for (int j = 0; j < 4; ++j) {
      int lab = m0 + j * 16 + row;
      gl_lds16(tblb + (size_t)lab * 128 + kc * 32 + k16s * 8, &As[kc][j * 16][0]);
    }
  }
  __syncthreads();

  floatx4 acc[4][4];
#pragma unroll
  for (int mi = 0; mi < 4; ++mi)
#pragma unroll
    for (int ni = 0; ni < 4; ++ni)
      acc[mi][ni] = (floatx4){hb1v[ni], hb1v[ni], hb1v[ni], hb1v[ni]};

  const int sel = (l15 >> 1) & 3;
#pragma unroll
  for (int kc = 0; kc < 4; ++kc) {
    short8 afr[4];
#pragma unroll
    for (int mi = 0; mi < 4; ++mi)
      afr[mi] = *(const short8*)&As[kc][mi * 16 + l15][(q ^ sel) * 8];
#pragma unroll
    for (int mi = 0; mi < 4; ++mi)
#pragma unroll
      for (int ni = 0; ni < 4; ++ni)
        acc[mi][ni] = __builtin_amdgcn_mfma_f32_16x16x32_bf16(afr[mi], bfrag[kc][ni], acc[mi][ni], 0, 0, 0);
  }

  // epilogue: C = sum hv*gelu_small(u); Ak = sum hv*gelu_small'(u)*Pk
#pragma unroll
  for (int mi = 0; mi < 4; ++mi) {
#pragma unroll
    for (int reg = 0; reg < 4; ++reg) {
      float sC = 0.f, s1 = 0.f, s2 = 0.f, s3 = 0.f, s4 = 0.f;
#pragma unroll
      for (int ni = 0; ni < 4; ++ni) {
        float u = acc[mi][ni][reg];
        float u2 = u * u;
        float gs = fmaf(GC, u2, 0.5f * u) - GD * u2 * u2;            // gelu_small(u)
        float gp = fmaf(-4.f * GD * u, u2, fmaf(2.f * GC, u, 0.5f)); // gelu_small'(u)
        sC = fmaf(hv[ni], gs, sC);
        float m = hv[ni] * gp;
        s1 = fmaf(m, Pv[0][ni], s1);
        s2 = fmaf(m, Pv[1][ni], s2);
        s3 = fmaf(m, Pv[2][ni], s3);
        s4 = fmaf(m, Pv[3][ni], s4);
      }
      sC = red16(sC); s1 = red16(s1); s2 = red16(s2); s3 = red16(s3); s4 = red16(s4);
      int r = mi * 16 + q * 4 + reg;
      if (l15 == 0) red[w][r][0] = sC;
      if (l15 == 1) red[w][r][1] = s1;
      if (l15 == 2) red[w][r][2] = s2;
      if (l15 == 3) red[w][r][3] = s3;
      if (l15 == 4) red[w][r][4] = s4;
    }
  }
  __syncthreads();
  {
    int r = tid >> 2, k = tid & 3;
    float v = red[0][r][k] + red[1][r][k] + red[2][r][k] + red[3][r][k];
    if (k == 0) v += hb2l;
    CA8[((size_t)(l * 256 + m0 + r)) * 8 + k] = v;
  }
  if (tid < 64) {
    float v = red[0][tid][4] + red[1][tid][4] + red[2][tid][4] + red[3][tid][4];
    CA8[((size_t)(l * 256 + m0 + tid)) * 8 + 4] = v;
  }
}

// ================= output kernel =================
__global__ void out_kernel(const int* __restrict__ y, const float* __restrict__ e,
                           const float* __restrict__ CA8, const float* __restrict__ Q,
                           float* __restrict__ outh) {
  __shared__ float Qs[512];
  const int t = threadIdx.x;
  const int base = blockIdx.x * 256;
  Qs[t] = Q[t];
  Qs[t + 256] = Q[t + 256];
  __syncthreads();
  const int b = (base + t) >> 6;
  const int l = t & 63;
  const float x = e[base + t];
  const int lab = y[b];
  const float* ca = CA8 + ((size_t)(l * 256 + lab)) * 8;
  const float4 c4 = *(const float4*)ca;   // C, A1, A2, A3
  const float a4 = ca[4];
  const float* qp = &Qs[l * 8];
  const float x2 = x * x, x3 = x2 * x, x4 = x2 * x2;
  float s = c4.x;
  s = fmaf(c4.y, x, s);
  s = fmaf(c4.z + qp[0], x2, s);
  s = fmaf(c4.w + qp[1], x3, s);
  s = fmaf(a4 + qp[2], x4, s);
  s = fmaf(qp[3], x4 * x, s);
  s = fmaf(qp[4], x4 * x2, s);
  s = fmaf(qp[5], x4 * x3, s);
  s = fmaf(qp[6], x4 * x4, s);
  outh[base + t] = tanhf(3.f * s);
}

extern "C" void kernel_launch(void* const* d_in, const int* in_sizes, int n_in,
                              void* d_out, int out_size, void* d_ws, size_t ws_size,
                              hipStream_t stream) {
  const int* y     = (const int*)d_in[0];
  const float* e   = (const float*)d_in[1];
  const float* emb = (const float*)d_in[2];
  const float* yW1 = (const float*)d_in[3];
  const float* yb1 = (const float*)d_in[4];
  const float* yW2 = (const float*)d_in[5];
  const float* yb2 = (const float*)d_in[6];
  const float* eW1 = (const float*)d_in[7];
  const float* eb1 = (const float*)d_in[8];
  const float* eW2 = (const float*)d_in[9];
  const float* eb2 = (const float*)d_in[10];
  const float* hW1 = (const float*)d_in[11];
  const float* hb1 = (const float*)d_in[12];
  const float* hW2 = (const float*)d_in[13];
  const float* hb2 = (const float*)d_in[14];

  float* outh   = (float*)d_out;                                     // h: [8192][64]
  uint4* outemb = (uint4*)((float*)d_out + (size_t)B_ROWS * L_DIM);  // y_embed f32 [8192][128]

  char* ws = (char*)d_ws;
  unsigned short* tblb = (unsigned short*)(ws + OFF_TBLB);
  unsigned short* Wtc  = (unsigned short*)(ws + OFF_WTC);
  float* hb1p = (float*)(ws + OFF_HB1P);
  float* P    = (float*)(ws + OFF_P);
  float* Q    = (float*)(ws + OFF_Q);
  float* CA8  = (float*)(ws + OFF_CA8);

  prep_kernel<<<dim3(1445), dim3(256), 0, stream>>>(hW1, hb1, eW1, eb1, eW2, eb2, emb,
                                                    yW1, yb1, yW2, yb2, y, hW2,
                                                    tblb, Wtc, hb1p, P, Q, outemb);
  tblgemm_kernel<<<dim3(4, 64), dim3(256), 0, stream>>>(tblb, Wtc, hb1p, P, hW2, hb2, CA8);
  out_kernel<<<dim3(B_ROWS * L_DIM / 256), dim3(256), 0, stream>>>(y, e, CA8, Q, outh);
}

// Round 6
// 122.660 us; speedup vs baseline: 1.9484x; 1.0267x over previous
//
#include <hip/hip_runtime.h>
#include <math.h>

typedef short short8 __attribute__((ext_vector_type(8)));
typedef float floatx4 __attribute__((ext_vector_type(4)));

#define B_ROWS 8192
#define L_DIM 64
#define MAXL 200
#define GC 0.39894228f
#define GD 0.0668178f

// workspace offsets (bytes)
#define OFF_TBLB 0u          // bf16 [256][128] (rows 200..255 zeroed)
#define OFF_WTC  65536u      // bf16 [64][4][256][32]
#define OFF_HB1P 4259840u    // f32 [64][256]
#define OFF_P    4325376u    // f32 [64][4][256]  (P1..P4)
#define OFF_Q    4587520u    // f32 [64][8]       (q for x^2,x^3,x^4 at 0..2; 3..6 unused)
#define OFF_CA8  4589568u    // f32 [256][64][8]  (lab-major: C,A1,A2',A3',A4',-,-,-)

__device__ __forceinline__ unsigned short f2b(float f) {
  union { float f; unsigned int i; } v; v.f = f;
  unsigned int r = (v.i + 0x7fffu + ((v.i >> 16) & 1u)) >> 16;
  return (unsigned short)r;
}
__device__ __forceinline__ float gelu_exact(float x) {
  float u = 0.7978845608028654f * x * fmaf(0.044715f, x * x, 1.0f);
  return 0.5f * x * (1.0f + tanhf(u));
}

__device__ __forceinline__ void gl_lds16(const void* g, void* l) {
  __builtin_amdgcn_global_load_lds(
      (const __attribute__((address_space(1))) unsigned int*)g,
      (__attribute__((address_space(3))) unsigned int*)l, 16, 0, 0);
}

template <int CTRL>
__device__ __forceinline__ float dpp_add(float v) {
  int t = __builtin_amdgcn_update_dpp(0, __float_as_int(v), CTRL, 0xf, 0xf, true);
  return v + __int_as_float(t);
}
__device__ __forceinline__ float red16(float v) {
  v = dpp_add<0xB1>(v);   // quad_perm xor1
  v = dpp_add<0x4E>(v);   // quad_perm xor2
  v = dpp_add<0x141>(v);  // row_half_mirror
  v = dpp_add<0x140>(v);  // row_mirror
  return v;
}

// ================= prep kernel =================
// [0,256):    Wtc bf16 chunks (l=bid>>2, kc=bid&3)
// [256,320):  per-l: W' = eW2@hW1_e -> P1..P4, hb1p (all bias folded), Q (delta^2 coeffs)
// [320,1344): y_embed output copy
// [1344,1444): y_h table (2 labels/block) -> tblb bf16
// 1444:       zero tblb pad rows 200..255
__global__ void prep_kernel(const float* __restrict__ hW1, const float* __restrict__ hb1,
                            const float* __restrict__ eW1, const float* __restrict__ eb1,
                            const float* __restrict__ eW2, const float* __restrict__ eb2,
                            const float* __restrict__ emb,
                            const float* __restrict__ yW1, const float* __restrict__ yb1,
                            const float* __restrict__ yW2, const float* __restrict__ yb2,
                            const int* __restrict__ y, const float* __restrict__ hW2,
                            unsigned short* __restrict__ tblb,
                            unsigned short* __restrict__ Wtc,
                            float* __restrict__ hb1p, float* __restrict__ P,
                            float* __restrict__ Q, uint4* __restrict__ outemb) {
  __shared__ float sh[2048];
  const int bid = blockIdx.x;
  const int t = threadIdx.x;
  if (bid < 256) {
    const int l = bid >> 2, kc = bid & 3;
    const float* W = hW1 + (size_t)l * 160 * 256;
    unsigned short* dst = Wtc + (((size_t)l * 4 + kc) * 256 + t) * 32;
#pragma unroll
    for (int g = 0; g < 4; ++g) {
      short8 o;
#pragma unroll
      for (int j = 0; j < 8; ++j)
        o[j] = (short)f2b(W[(size_t)(kc * 32 + g * 8 + j) * 256 + t]);
      *(short8*)&dst[g * 8] = o;
    }
  } else if (bid < 320) {
    const int l = bid - 256;
    sh[t] = eW2[t];                 // eW2: [16][32]
    sh[t + 256] = eW2[t + 256];
    if (t < 32) sh[512 + t] = eb2[t];
    __syncthreads();
    const float* W = hW1 + (size_t)l * 160 * 256;
    float accW[16];
#pragma unroll
    for (int j = 0; j < 16; ++j) accW[j] = 0.f;
    float hacc = 0.f;
    for (int i = 0; i < 32; ++i) {
      float v = W[(size_t)(128 + i) * 256 + t];
      hacc = fmaf(sh[512 + i], v, hacc);
#pragma unroll
      for (int j = 0; j < 16; ++j) accW[j] = fmaf(sh[j * 32 + i], v, accW[j]);
    }
    // gelu_small(w x + b) = e0 + e1 x + e2 x^2 + e3 x^3 + e4 x^4
    float P0 = 0.f, P1 = 0.f, P2 = 0.f, P3 = 0.f, P4 = 0.f;
    for (int j = 0; j < 16; ++j) {
      float w = eW1[j], b = eb1[j];
      float w2 = w * w, b2 = b * b;
      float e0 = 0.5f * b + GC * b2 - GD * b2 * b2;
      float e1 = w * (0.5f + 2.f * GC * b - 4.f * GD * b * b2);
      float e2 = w2 * (GC - 6.f * GD * b2);
      float e3 = -4.f * GD * w2 * w * b;
      float e4 = -GD * w2 * w2;
      float a = accW[j];
      P0 = fmaf(e0, a, P0); P1 = fmaf(e1, a, P1); P2 = fmaf(e2, a, P2);
      P3 = fmaf(e3, a, P3); P4 = fmaf(e4, a, P4);
    }
    hb1p[l * 256 + t] = hb1[l * 256 + t] + hacc + P0;
    P[((size_t)l * 4 + 0) * 256 + t] = P1;
    P[((size_t)l * 4 + 1) * 256 + t] = P2;
    P[((size_t)l * 4 + 2) * 256 + t] = P3;
    P[((size_t)l * 4 + 3) * 256 + t] = P4;
    __syncthreads();  // done with sE/sB
    float cw = GC * hW2[l * 256 + t];
    sh[t * 8 + 0] = cw * P1 * P1;                          // x^2
    sh[t * 8 + 1] = cw * 2.f * P1 * P2;                    // x^3
    sh[t * 8 + 2] = cw * (2.f * P1 * P3 + P2 * P2);        // x^4
    __syncthreads();
    if (t < 3) {
      float s = 0.f;
      for (int n = 0; n < 256; ++n) s += sh[n * 8 + t];
      Q[l * 8 + t] = s;
    }
  } else if (bid < 1344) {
    const int row = (bid - 320) * 8 + (t >> 5);
    const int c = t & 31;
    outemb[row * 32 + c] = ((const uint4*)emb)[y[row] * 32 + c];
  } else if (bid < 1444) {
    const int lab = (bid - 1344) * 2 + (t >> 7);
    const int j = t & 127;
    float* mid = sh + (t >> 7) * 128;
    float acc = yb1[j];
    for (int c = 0; c < 128; ++c)
      acc = fmaf(emb[lab * 128 + c], yW1[c * 128 + j], acc);
    mid[j] = gelu_exact(acc);
    __syncthreads();
    float acc2 = yb2[j];
    for (int c = 0; c < 128; ++c)
      acc2 = fmaf(mid[c], yW2[c * 128 + j], acc2);
    tblb[lab * 128 + j] = f2b(acc2);
  } else {
    unsigned int* tz = (unsigned int*)tblb;
    for (int i = t; i < 3584; i += 256) tz[12800 + i] = 0u;  // rows 200..255
  }
}

// ================= table GEMM: U = tblb @ hW1_y + bias -> CA8[lab][l] =================
__global__ void tblgemm_kernel(const unsigned short* __restrict__ tblb,
                               const unsigned short* __restrict__ Wtc,
                               const float* __restrict__ hb1p,
                               const float* __restrict__ P,
                               const float* __restrict__ hW2,
                               const float* __restrict__ hb2,
                               const float* __restrict__ Q,
                               float* __restrict__ CA8) {
  const int l = blockIdx.y;
  const int m0 = blockIdx.x * 64;   // lab tile base
  const int tid = threadIdx.x;
  const int w = tid >> 6, lane = tid & 63;
  const int l15 = lane & 15, q = lane >> 4;

  __shared__ __align__(16) unsigned short As[4][64][32];  // 16 KB, swizzled slots
  __shared__ float red[4][64][8];                         // 8 KB

  short8 bfrag[4][4];
#pragma unroll
  for (int kc = 0; kc < 4; ++kc)
#pragma unroll
    for (int ni = 0; ni < 4; ++ni)
      bfrag[kc][ni] = *(const short8*)&Wtc[(((size_t)l * 4 + kc) * 256 + w * 64 + ni * 16 + l15) * 32 + q * 8];

  float hv[4], hb1v[4], Pv[4][4];
#pragma unroll
  for (int ni = 0; ni < 4; ++ni) {
    int n = w * 64 + ni * 16 + l15;
    hv[ni] = hW2[l * 256 + n];
    hb1v[ni] = hb1p[l * 256 + n];
#pragma unroll
    for (int k = 0; k < 4; ++k) Pv[k][ni] = P[((size_t)l * 4 + k) * 256 + n];
  }
  const float hb2l = hb2[l];

  {  // stage A: wave w loads kc=w chunk for all 64 rows
    const int kc = w;
    const int row = lane >> 2;
    const int k16 = lane & 3;
    const int k16s = k16 ^ ((row >> 1) & 3);
#pragma unroll
    for (int j = 0; j < 4; ++j) {
      int lab = m0 + j * 16 + row;
      gl_lds16(tblb + (size_t)lab * 128 + kc * 32 + k16s * 8, &As[kc][j * 16][0]);
    }
  }
  __syncthreads();

  floatx4 acc[4][4];
#pragma unroll
  for (int mi = 0; mi < 4; ++mi)
#pragma unroll
    for (int ni = 0; ni < 4; ++ni)
      acc[mi][ni] = (floatx4){hb1v[ni], hb1v[ni], hb1v[ni], hb1v[ni]};

  const int sel = (l15 >> 1) & 3;
#pragma unroll
  for (int kc = 0; kc < 4; ++kc) {
    short8 afr[4];
#pragma unroll
    for (int mi = 0; mi < 4; ++mi)
      afr[mi] = *(const short8*)&As[kc][mi * 16 + l15][(q ^ sel) * 8];
#pragma unroll
    for (int mi = 0; mi < 4; ++mi)
#pragma unroll
      for (int ni = 0; ni < 4; ++ni)
        acc[mi][ni] = __builtin_amdgcn_mfma_f32_16x16x32_bf16(afr[mi], bfrag[kc][ni], acc[mi][ni], 0, 0, 0);
  }

  // epilogue: C = sum hv*gelu_small(u); Ak = sum hv*gelu_small'(u)*Pk
#pragma unroll
  for (int mi = 0; mi < 4; ++mi) {
#pragma unroll
    for (int reg = 0; reg < 4; ++reg) {
      float sC = 0.f, s1 = 0.f, s2 = 0.f, s3 = 0.f, s4 = 0.f;
#pragma unroll
      for (int ni = 0; ni < 4; ++ni) {
        float u = acc[mi][ni][reg];
        float u2 = u * u;
        float gs = fmaf(GC, u2, 0.5f * u) - GD * u2 * u2;            // gelu_small(u)
        float gp = fmaf(-4.f * GD * u, u2, fmaf(2.f * GC, u, 0.5f)); // gelu_small'(u)
        sC = fmaf(hv[ni], gs, sC);
        float m = hv[ni] * gp;
        s1 = fmaf(m, Pv[0][ni], s1);
        s2 = fmaf(m, Pv[1][ni], s2);
        s3 = fmaf(m, Pv[2][ni], s3);
        s4 = fmaf(m, Pv[3][ni], s4);
      }
      sC = red16(sC); s1 = red16(s1); s2 = red16(s2); s3 = red16(s3); s4 = red16(s4);
      int r = mi * 16 + q * 4 + reg;
      if (l15 == 0) red[w][r][0] = sC;
      if (l15 == 1) red[w][r][1] = s1;
      if (l15 == 2) red[w][r][2] = s2;
      if (l15 == 3) red[w][r][3] = s3;
      if (l15 == 4) red[w][r][4] = s4;
    }
  }
  __syncthreads();
  {
    int r = tid >> 2, k = tid & 3;
    float v = red[0][r][k] + red[1][r][k] + red[2][r][k] + red[3][r][k];
    if (k == 0) v += hb2l;
    if (k >= 2) v += Q[l * 8 + (k - 2)];   // fold q2 (x^2), q3 (x^3)
    CA8[((size_t)(m0 + r) * 64 + l) * 8 + k] = v;
  }
  if (tid < 64) {
    float v = red[0][tid][4] + red[1][tid][4] + red[2][tid][4] + red[3][tid][4] + Q[l * 8 + 2];
    CA8[((size_t)(m0 + tid) * 64 + l) * 8 + 4] = v;
  }
}

// ================= output kernel: h = tanh(3*(C + A1 x + A2'x^2 + A3'x^3 + A4'x^4)) =================
__global__ void out_kernel(const int* __restrict__ y, const float* __restrict__ e,
                           const float* __restrict__ CA8,
                           float* __restrict__ outh) {
  const int idx = blockIdx.x * 256 + threadIdx.x;
  const int b = idx >> 6;
  const int l = idx & 63;
  const float x = e[idx];
  const int lab = y[b];
  const float* ca = CA8 + ((size_t)lab * 64 + l) * 8;   // wave reads contiguous 2 KB
  const float4 c4 = *(const float4*)ca;   // C, A1, A2', A3'
  const float a4 = ca[4];
  const float x2 = x * x;
  float s = fmaf(c4.y, x, c4.x);
  s = fmaf(c4.z, x2, s);
  s = fmaf(c4.w, x2 * x, s);
  s = fmaf(a4, x2 * x2, s);
  outh[idx] = tanhf(3.f * s);
}

extern "C" void kernel_launch(void* const* d_in, const int* in_sizes, int n_in,
                              void* d_out, int out_size, void* d_ws, size_t ws_size,
                              hipStream_t stream) {
  const int* y     = (const int*)d_in[0];
  const float* e   = (const float*)d_in[1];
  const float* emb = (const float*)d_in[2];
  const float* yW1 = (const float*)d_in[3];
  const float* yb1 = (const float*)d_in[4];
  const float* yW2 = (const float*)d_in[5];
  const float* yb2 = (const float*)d_in[6];
  const float* eW1 = (const float*)d_in[7];
  const float* eb1 = (const float*)d_in[8];
  const float* eW2 = (const float*)d_in[9];
  const float* eb2 = (const float*)d_in[10];
  const float* hW1 = (const float*)d_in[11];
  const float* hb1 = (const float*)d_in[12];
  const float* hW2 = (const float*)d_in[13];
  const float* hb2 = (const float*)d_in[14];

  float* outh   = (float*)d_out;                                     // h: [8192][64]
  uint4* outemb = (uint4*)((float*)d_out + (size_t)B_ROWS * L_DIM);  // y_embed f32 [8192][128]

  char* ws = (char*)d_ws;
  unsigned short* tblb = (unsigned short*)(ws + OFF_TBLB);
  unsigned short* Wtc  = (unsigned short*)(ws + OFF_WTC);
  float* hb1p = (float*)(ws + OFF_HB1P);
  float* P    = (float*)(ws + OFF_P);
  float* Q    = (float*)(ws + OFF_Q);
  float* CA8  = (float*)(ws + OFF_CA8);

  prep_kernel<<<dim3(1445), dim3(256), 0, stream>>>(hW1, hb1, eW1, eb1, eW2, eb2, emb,
                                                    yW1, yb1, yW2, yb2, y, hW2,
                                                    tblb, Wtc, hb1p, P, Q, outemb);
  tblgemm_kernel<<<dim3(4, 64), dim3(256), 0, stream>>>(tblb, Wtc, hb1p, P, hW2, hb2, Q, CA8);
  out_kernel<<<dim3(B_ROWS * L_DIM / 256), dim3(256), 0, stream>>>(y, e, CA8, outh);
}